// Round 13
// baseline (427.786 us; speedup 1.0000x reference)
//
#include <hip/hip_runtime.h>
#include <math.h>

#define BATCH   16384
#define DIMS    64
#define WID     128
#define KN      8
#define NP      23        // 3*KN - 1
#define NCOL    (DIMS * NP)   // 1472 param columns
#define NLAYERS 8
#define BI_F    4.0f
#define GRP     92        // param cols per 4-dim group
#define NGRP    16        // groups per layer
#define NITER   (NLAYERS * NGRP)   // 128 flat groups
#define PCP     104       // Pc row pitch in shorts (208 B, 16B-aligned rows)
#define HHP     72        // Hs-half row pitch in shorts (144 B; 36dw%32=4)
#define XBP     72        // Xb row pitch in shorts (144 B; 36dw%32=4)
#define LOG2E   1.44269504f

#define PF_WOUT (NLAYERS * NCOL * WID)        // per-flow Wout elems: 1,507,328
#define PF_W1   (NLAYERS * WID * DIMS)        // per-flow W1 elems:   65,536

typedef short s16x8 __attribute__((ext_vector_type(8)));
typedef unsigned short u16x8 __attribute__((ext_vector_type(8)));
typedef float f32x4 __attribute__((ext_vector_type(4)));

__device__ __forceinline__ unsigned short f2bf(float f) {
    unsigned int u = __builtin_bit_cast(unsigned int, f);
    unsigned int r = (u + 0x7FFFu + ((u >> 16) & 1u)) >> 16;
    return (unsigned short)r;
}
__device__ __forceinline__ float bf2f(unsigned short u) {
    return __builtin_bit_cast(float, (unsigned int)u << 16);
}
// bf16-pair dword -> two f32 (lo: shift up; hi: mask in place).
__device__ __forceinline__ float bfLO(unsigned int u) {
    return __builtin_bit_cast(float, u << 16);
}
__device__ __forceinline__ float bfHI(unsigned int u) {
    return __builtin_bit_cast(float, u & 0xffff0000u);
}
// HW packed f32->bf16 RNE: dst = {bf16(a) lo16, bf16(b) hi16}. 1 inst/pair.
__device__ __forceinline__ unsigned int cvtpk_bf16(float a, float b) {
    unsigned int r;
    asm("v_cvt_pk_bf16_f32 %0, %1, %2" : "=v"(r) : "v"(a), "v"(b));
    return r;
}

// global -> LDS direct DMA, 16B per lane (wave-uniform LDS base + lane*16).
__device__ __forceinline__ void stage16(const unsigned short* g, unsigned short* l) {
    __builtin_amdgcn_global_load_lds(
        (__attribute__((address_space(1))) void*)g,
        (__attribute__((address_space(3))) void*)l,
        16, 0, 0);
}

// ---------------------------------------------------------------------------
// Pre-mask MADE weights -> bf16 workspace (K-swizzled columns, log2e
// pre-scale on womask; unchanged from proven R7-R11 versions).
// ---------------------------------------------------------------------------
__global__ __launch_bounds__(256) void premask_kernel(
    const float* __restrict__ f_wout, const float* __restrict__ g_wout,
    const float* __restrict__ f_w1,   const float* __restrict__ g_w1,
    unsigned short* __restrict__ womask, unsigned short* __restrict__ w1mask)
{
    const int idx    = blockIdx.x * 256 + threadIdx.x;
    const int stride = gridDim.x * 256;

    const int totw = 2 * PF_WOUT;
    for (int i = idx; i < totw; i += stride) {
        int fl = i / PF_WOUT;
        int r  = i % PF_WOUT;
        int h  = r % WID;
        int o  = (r / WID) % NCOL;              // layer-local param col
        int d  = o / NP;
        int hd = h % (DIMS - 1) + 1;            // hid_deg
        const float* src = fl ? g_wout : f_wout;
        unsigned short v = (hd <= d) ? f2bf(src[r] * LOG2E) : (unsigned short)0;
        const int dst = i - h + (h ^ ((o & 7) << 4));   // swizzled k position
        womask[dst] = v;
    }

    const int tot1 = 2 * PF_W1;
    for (int i = idx; i < tot1; i += stride) {
        int fl = i / PF_W1;
        int r  = i % PF_W1;
        int c  = r % DIMS;
        int w  = (r / DIMS) % WID;
        int deg = w % (DIMS - 1) + 1;           // hid_deg
        const float* src = fl ? g_w1 : f_w1;
        w1mask[i] = (c < deg) ? f2bf(src[r]) : (unsigned short)0;
    }
}

// ---------------------------------------------------------------------------
// FUSED 8-layer MAF kernel, ROUND 12/13: software-pipelined group loop.
//   Per iteration gi (flat group 0..127):
//     DMA(gi+1 -> Wl[other]) ; [layer start: spline(gi-1); GEMM1(l)]
//     MFMA(gi, Wl[cur]) INTERLEAVED (straight-line) with spline(gi-1)
//     Pc-store(gi) ; ONE __syncthreads (drains DMA + Wl-read sync).
//   vs R11's {MFMA -> B1 -> DMA -> spline -> B2}: MFMA pipe overlaps spline
//   VALU within each wave; 254 -> 128 barriers; DMA hidden under full iter.
// Enablers: Wl DOUBLE-buffered (+23.5KB); Xb (x ping-pong) in BF16
// (-16.4KB; xa A-frags load directly as bf16 -- GEMM inputs bit-identical
// to R11 since xa was already RNE(x); only spline xraw is rounded);
// Hs staged in two 64-col halves through S (-4KB).
// LDS: Wl 47,104 + S 13,312 + Xb 18,432 = 78,848 B -> 2 blocks/CU.
// ---------------------------------------------------------------------------
__global__ __launch_bounds__(256, 2)
void flow8_kernel(
    const float* __restrict__ xin_f, const float* __restrict__ xin_g,
    float* __restrict__ xout_f,      float* __restrict__ xout_g,
    const unsigned short* __restrict__ w1m_f, const unsigned short* __restrict__ w1m_g,
    const float* __restrict__ b1_f,  const float* __restrict__ b1_g,
    const unsigned short* __restrict__ wom_f, const unsigned short* __restrict__ wom_g,
    const float* __restrict__ bo_f,  const float* __restrict__ bo_g,
    float* __restrict__ ld_f,        float* __restrict__ ld_g)
{
    // Wl: double-buffered weight tile [buf][92 cols][128 k] (pre-swizzled).
    __shared__ __align__(16) unsigned short Wl[2][GRP * WID];     // 47,104 B
    // S: per-wave overlay. Pc row-major [16][104] (1664); Hs-HALF view
    //    [16][72] (1152, cols 0..63 then 64..127 sequentially; dead by Pc).
    __shared__ __align__(16) unsigned short S[4][16 * PCP];       // 13,312 B
    // Xb: x ping-pong, BF16, [buf][wv][16 rows][pitch 72].
    __shared__ __align__(16) unsigned short Xb[2][4][16][XBP];    // 18,432 B

    const int t    = threadIdx.x;
    const int wv   = t >> 6;          // wave 0..3
    const int ln   = t & 63;
    const int m    = ln & 15;         // row-in-tile / col-in-tile index
    const int q    = ln >> 4;         // quad
    const int flow = blockIdx.y;
    const int r0   = blockIdx.x * 64 + wv * 16;   // this wave's first batch row

    const float* xin          = flow ? xin_g : xin_f;
    float*       xout         = flow ? xout_g : xout_f;
    const unsigned short* w1m = flow ? w1m_g : w1m_f;
    const float* b1           = flow ? b1_g  : b1_f;
    const unsigned short* wom = flow ? wom_g : wom_f;
    const float* bo           = flow ? bo_g  : bo_f;
    float*       ldp          = flow ? ld_g  : ld_f;

    unsigned short* sw = &S[wv][0];

    // ---- Xb[0] init: wave's 16 rows, f32 global -> bf16 pairs ----
    {
        const int row = ln >> 2;
        const int c0  = (ln & 3) * 16;
        const float* srcr = xin + (size_t)(r0 + row) * DIMS + c0;
        float4 v0 = *(const float4*)(srcr);
        float4 v1 = *(const float4*)(srcr + 4);
        float4 v2 = *(const float4*)(srcr + 8);
        float4 v3 = *(const float4*)(srcr + 12);
        uint4 pa, pb;
        pa.x = cvtpk_bf16(v0.x, v0.y); pa.y = cvtpk_bf16(v0.z, v0.w);
        pa.z = cvtpk_bf16(v1.x, v1.y); pa.w = cvtpk_bf16(v1.z, v1.w);
        pb.x = cvtpk_bf16(v2.x, v2.y); pb.y = cvtpk_bf16(v2.z, v2.w);
        pb.z = cvtpk_bf16(v3.x, v3.y); pb.w = cvtpk_bf16(v3.z, v3.w);
        *(u16x8*)&Xb[0][wv][row][c0]     = __builtin_bit_cast(u16x8, pa);
        *(u16x8*)&Xb[0][wv][row][c0 + 8] = __builtin_bit_cast(u16x8, pb);
    }
    asm volatile("" ::: "memory");

    // ---- prologue: DMA-stage flat group 0 -> Wl[0] ----
    {
        const unsigned short* src = wom + ln * 8;
        #pragma unroll
        for (int i = 0; i < 6; ++i) {
            const int c = wv + 4 * i;
            if (c < 23) stage16(src + c * 512, Wl[0] + c * 512);
        }
    }

    // ---- P-store column map: col o = nt*16+m -> row-major dim*24+j = o+dim.
    int offn[6];
    #pragma unroll
    for (int nt = 0; nt < 6; ++nt) {
        const int o = nt * 16 + m;
        offn[nt] = o + (o >= 23) + (o >= 46) + (o >= 69) + (o >= 92);
    }

    float ldsum = 0.0f;
    s16x8 af[4];
    float bnx[6];

    // ---- GEMM1 (layer l): xa direct-bf16 from Xb[l&1]; H via two 64-col
    //      halves through S (Hs view, pitch 72); sets af[0..3]. ----
    auto gemm1 = [&](int l) {
        const unsigned short* w1m_l = w1m + (size_t)l * WID * DIMS;
        const float* b1_l           = b1 + (size_t)l * WID;
        const unsigned short* xb    = &Xb[l & 1][wv][m][0];
        s16x8 xa0 = *(const s16x8*)(xb + q * 8);
        s16x8 xa1 = *(const s16x8*)(xb + 32 + q * 8);

        f32x4 hacc[8];
        #pragma unroll
        for (int nt = 0; nt < 8; ++nt) {
            float bv = b1_l[nt * 16 + m];
            hacc[nt] = (f32x4){bv, bv, bv, bv};
        }
        #pragma unroll
        for (int nt = 0; nt < 8; ++nt) {
            s16x8 b0 = *(const s16x8*)(w1m_l + (nt * 16 + m) * DIMS + q * 8);
            hacc[nt] = __builtin_amdgcn_mfma_f32_16x16x32_bf16(xa0, b0, hacc[nt], 0, 0, 0);
        }
        #pragma unroll
        for (int nt = 0; nt < 8; ++nt) {
            s16x8 b1f = *(const s16x8*)(w1m_l + (nt * 16 + m) * DIMS + 32 + q * 8);
            hacc[nt] = __builtin_amdgcn_mfma_f32_16x16x32_bf16(xa1, b1f, hacc[nt], 0, 0, 0);
        }
        // half 0: H cols 0..63 (nt 0..3) -> Hs[16][72], read af[0..1]
        #pragma unroll
        for (int nt = 0; nt < 4; ++nt) {
            const int c = nt * 16 + m;
            unsigned int p0 = cvtpk_bf16(fmaxf(hacc[nt][0], 0.0f), fmaxf(hacc[nt][1], 0.0f));
            unsigned int p1 = cvtpk_bf16(fmaxf(hacc[nt][2], 0.0f), fmaxf(hacc[nt][3], 0.0f));
            sw[(q * 4 + 0) * HHP + c] = (unsigned short)p0;
            sw[(q * 4 + 1) * HHP + c] = (unsigned short)(p0 >> 16);
            sw[(q * 4 + 2) * HHP + c] = (unsigned short)p1;
            sw[(q * 4 + 3) * HHP + c] = (unsigned short)(p1 >> 16);
        }
        asm volatile("" ::: "memory");
        af[0] = *(const s16x8*)&sw[m * HHP + q * 8];
        af[1] = *(const s16x8*)&sw[m * HHP + 32 + q * 8];
        asm volatile("" ::: "memory");
        // half 1: H cols 64..127 (nt 4..7) reuse the same region
        #pragma unroll
        for (int nt = 4; nt < 8; ++nt) {
            const int c = (nt - 4) * 16 + m;
            unsigned int p0 = cvtpk_bf16(fmaxf(hacc[nt][0], 0.0f), fmaxf(hacc[nt][1], 0.0f));
            unsigned int p1 = cvtpk_bf16(fmaxf(hacc[nt][2], 0.0f), fmaxf(hacc[nt][3], 0.0f));
            sw[(q * 4 + 0) * HHP + c] = (unsigned short)p0;
            sw[(q * 4 + 1) * HHP + c] = (unsigned short)(p0 >> 16);
            sw[(q * 4 + 2) * HHP + c] = (unsigned short)p1;
            sw[(q * 4 + 3) * HHP + c] = (unsigned short)(p1 >> 16);
        }
        asm volatile("" ::: "memory");
        af[2] = *(const s16x8*)&sw[m * HHP + q * 8];
        af[3] = *(const s16x8*)&sw[m * HHP + 32 + q * 8];
        asm volatile("" ::: "memory");
    };

    // ---- spline for flat group pgi (reads Pc stored at iter pgi) ----
    auto spline = [&](int pgi) {
        const int pl = pgi >> 4;
        const int pg = pgi & 15;
        const int d  = pg * 4 + q;
        const int xb = pl & 1;

        const unsigned short* pr = &sw[m * PCP + q * 24];
        u16x8 w0 = *(const u16x8*)(pr);
        u16x8 w1 = *(const u16x8*)(pr + 8);
        u16x8 w2 = *(const u16x8*)(pr + 16);
        uint4 r0 = __builtin_bit_cast(uint4, w0);
        uint4 r1 = __builtin_bit_cast(uint4, w1);
        uint4 r2 = __builtin_bit_cast(uint4, w2);

        float pp[NP];
        pp[0]  = bfLO(r0.x); pp[1]  = bfHI(r0.x);
        pp[2]  = bfLO(r0.y); pp[3]  = bfHI(r0.y);
        pp[4]  = bfLO(r0.z); pp[5]  = bfHI(r0.z);
        pp[6]  = bfLO(r0.w); pp[7]  = bfHI(r0.w);
        pp[8]  = bfLO(r1.x); pp[9]  = bfHI(r1.x);
        pp[10] = bfLO(r1.y); pp[11] = bfHI(r1.y);
        pp[12] = bfLO(r1.z); pp[13] = bfHI(r1.z);
        pp[14] = bfLO(r1.w); pp[15] = bfHI(r1.w);
        pp[16] = bfLO(r2.x); pp[17] = bfHI(r2.x);
        pp[18] = bfLO(r2.y); pp[19] = bfHI(r2.y);
        pp[20] = bfLO(r2.z); pp[21] = bfHI(r2.z);
        pp[22] = bfLO(r2.w);

        const float xraw = bf2f(Xb[xb][wv][m][d]);

        float ew[KN], eh[KN];
        #pragma unroll
        for (int j = 0; j < KN; ++j) {
            ew[j] = exp2f(pp[j]);
            eh[j] = exp2f(pp[8 + j]);
        }
        const float sw_ = ((ew[0] + ew[1]) + (ew[2] + ew[3]))
                        + ((ew[4] + ew[5]) + (ew[6] + ew[7]));
        const float sh_ = ((eh[0] + eh[1]) + (eh[2] + eh[3]))
                        + ((eh[4] + eh[5]) + (eh[6] + eh[7]));
        const float cmul = 8.0f / 1.01f;
        const float cadd = 0.00125f * (8.0f / 1.01f);
        const float rw = cmul / sw_, rh = cmul / sh_;
        float width[KN], height[KN];
        #pragma unroll
        for (int j = 0; j < KN; ++j) {
            width[j]  = fmaf(ew[j], rw, cadd);
            height[j] = fmaf(eh[j], rh, cadd);
        }

        const bool inside = (xraw > -BI_F) && (xraw < BI_F);
        const float xcl = fminf(fmaxf(xraw, -BI_F), BI_F);

        // Knot scan, i=0 peeled; tracks SELECTED raw deriv params; softplus
        // deferred to the 2 selected (cc monotone: cc1 <=> k>=1, cc7 <=> k==7).
        float cx = -BI_F + width[0], cy = -BI_F + height[0];
        float xk = -BI_F, yk = -BI_F, xk1 = cx, yk1 = cy;
        float selk = pp[16], selk1 = pp[16];
        bool cc1 = false, cc7 = false;
        #pragma unroll
        for (int i = 1; i < KN; ++i) {
            const float nx = cx + width[i];
            const float ny = cy + height[i];
            const bool cc = (xcl >= cx);
            if (i == 1) cc1 = cc;
            if (i == 7) cc7 = cc;
            xk  = cc ? cx : xk;    yk  = cc ? cy : yk;
            xk1 = cc ? nx : xk1;   yk1 = cc ? ny : yk1;
            selk = cc ? pp[15 + i] : selk;
            if (i < 7) selk1 = cc ? pp[16 + i] : selk1;
            cx = nx; cy = ny;
        }
        const float ta = exp2f(selk);
        const float da = fmaf(__log2f(1.0f + ta), 0.69314718f, 0.001f);
        const float tb = exp2f(selk1);
        const float db = fmaf(__log2f(1.0f + tb), 0.69314718f, 0.001f);
        const float dk  = cc1 ? da : 1.0f;
        const float dk1 = cc7 ? 1.0f : db;

        const float invw = 1.0f / (xk1 - xk);
        const float sk   = (yk1 - yk) * invw;
        const float xi   = (xcl - xk) * invw;
        const float omx  = 1.0f - xi;
        const float den  = sk + (dk1 + dk - 2.0f * sk) * xi * omx;
        const float rden = 1.0f / den;
        float outv = fmaf((yk1 - yk) * (sk * xi * xi + dk * xi * omx), rden, yk);
        const float numl = dk1 * xi * xi + 2.0f * sk * xi * omx + dk * omx * omx;
        float ldj = __logf(sk * sk * numl * rden * rden);
        outv = inside ? outv : xraw;
        ldj  = inside ? ldj : 0.0f;

        Xb[xb ^ 1][wv][m][63 - d] = (unsigned short)cvtpk_bf16(outv, outv);
        ldsum += ldj;
    };

    // ---- prologue: GEMM1 layer 0 (covers DMA g0) + bias(0) ----
    gemm1(0);
    #pragma unroll
    for (int nt = 0; nt < 6; ++nt)
        bnx[nt] = bo[nt * 16 + m] * LOG2E;     // gi=0 cols 0..95 in-bounds

    __syncthreads();                 // g0 weights resident for all waves

    #pragma unroll 1
    for (int gi = 0; gi < NITER; ++gi) {
        const int g = gi & 15;

        // ---- issue DMA for gi+1 into the idle buffer (drained at the
        //      barrier below; full-iteration latency window) ----
        if (gi < NITER - 1) {
            const int n = gi + 1, l2 = n >> 4, g2 = n & 15;
            const unsigned short* src = wom +
                ((size_t)l2 * NCOL + (size_t)g2 * GRP) * WID + ln * 8;
            unsigned short* dst = &Wl[n & 1][0];
            #pragma unroll
            for (int i = 0; i < 6; ++i) {
                const int c = wv + 4 * i;
                if (c < 23) stage16(src + c * 512, dst + c * 512);
            }
        }

        // ---- layer start: finish previous group's spline (reads Pc before
        //      GEMM1's Hs overwrites it), then GEMM1 for this layer ----
        if (g == 0 && gi > 0) {
            spline(gi - 1);
            asm volatile("" ::: "memory");
            gemm1(gi >> 4);
        }

        // ---- MFMA group gi from Wl[gi&1] (swizzled) ----
        f32x4 acc[6];
        #pragma unroll
        for (int nt = 0; nt < 6; ++nt)
            acc[nt] = (f32x4){bnx[nt], bnx[nt], bnx[nt], bnx[nt]};

        const unsigned short* wl = &Wl[gi & 1][0];
        const int swz = ((g * 4 + m) & 7) << 4;
        #pragma unroll
        for (int ks = 0; ks < 4; ++ks) {
            #pragma unroll
            for (int nt = 0; nt < 6; ++nt) {
                const s16x8 bfr = *(const s16x8*)&wl[
                    (nt * 16 + m) * WID + ((ks * 32 + q * 8) ^ swz)];
                acc[nt] = __builtin_amdgcn_mfma_f32_16x16x32_bf16(af[ks], bfr, acc[nt], 0, 0, 0);
            }
        }

        // ---- bias prefetch for gi+1 (bnx consumed above) ----
        if (gi < NITER - 1) {
            const int n = gi + 1, l2 = n >> 4, g2 = n & 15;
            #pragma unroll
            for (int nt = 0; nt < 6; ++nt) {
                int o = g2 * GRP + nt * 16 + m;
                o = (o < NCOL) ? o : (NCOL - 1);
                bnx[nt] = bo[(size_t)l2 * NCOL + o] * LOG2E;
            }
        }

        // ---- mid-layer: spline(gi-1) here, straight-line with the MFMA
        //      above -> scheduler overlaps matrix pipe with spline VALU ----
        if (g != 0) {
            spline(gi - 1);
        }
        asm volatile("" ::: "memory");   // spline Pc reads before Pc overwrite

        // ---- Pc store (row-major, pitch 104) from acc ----
        #pragma unroll
        for (int nt = 0; nt < 6; ++nt) {
            const int cb = q * 4 * PCP + offn[nt];
            unsigned int p0 = cvtpk_bf16(acc[nt][0], acc[nt][1]);
            unsigned int p1 = cvtpk_bf16(acc[nt][2], acc[nt][3]);
            sw[cb          ] = (unsigned short)p0;
            sw[cb +     PCP] = (unsigned short)(p0 >> 16);
            sw[cb + 2 * PCP] = (unsigned short)p1;
            sw[cb + 3 * PCP] = (unsigned short)(p1 >> 16);
        }

        __syncthreads();   // sync Wl reads + drain DMA(gi+1) for all waves
    }

    // ---- drain: last group's spline ----
    spline(NITER - 1);
    asm volatile("" ::: "memory");

    // ---- epilogue: xout (f32) from final Xb[0] (layer 8 -> buf 8&1 = 0) ----
    {
        const int row = ln >> 2;
        const int c0  = (ln & 3) * 16;
        u16x8 ua = *(const u16x8*)&Xb[0][wv][row][c0];
        u16x8 ub = *(const u16x8*)&Xb[0][wv][row][c0 + 8];
        uint4 ra = __builtin_bit_cast(uint4, ua);
        uint4 rb = __builtin_bit_cast(uint4, ub);
        float* dstr = xout + (size_t)(r0 + row) * DIMS + c0;
        float4 o0 = {bfLO(ra.x), bfHI(ra.x), bfLO(ra.y), bfHI(ra.y)};
        float4 o1 = {bfLO(ra.z), bfHI(ra.z), bfLO(ra.w), bfHI(ra.w)};
        float4 o2 = {bfLO(rb.x), bfHI(rb.x), bfLO(rb.y), bfHI(rb.y)};
        float4 o3 = {bfLO(rb.z), bfHI(rb.z), bfLO(rb.w), bfHI(rb.w)};
        *(float4*)(dstr)      = o0;
        *(float4*)(dstr + 4)  = o1;
        *(float4*)(dstr + 8)  = o2;
        *(float4*)(dstr + 12) = o3;
    }

    // ---- ld: reduce q-quarters, one plain store per row ----
    float v = ldsum + __shfl_xor(ldsum, 16, 64);
    v = v + __shfl_xor(v, 32, 64);
    if (ln < 16) {
        ldp[r0 + ln] = v;
    }
}

// ---------------------------------------------------------------------------
extern "C" void kernel_launch(void* const* d_in, const int* in_sizes, int n_in,
                              void* d_out, int out_size, void* d_ws, size_t ws_size,
                              hipStream_t stream)
{
    const float* x      = (const float*)d_in[0];
    const float* y      = (const float*)d_in[1];
    const float* f_W1   = (const float*)d_in[2];
    const float* f_b1   = (const float*)d_in[3];
    const float* f_Wout = (const float*)d_in[4];
    const float* f_bout = (const float*)d_in[5];
    const float* g_W1   = (const float*)d_in[6];
    const float* g_b1   = (const float*)d_in[7];
    const float* g_Wout = (const float*)d_in[8];
    const float* g_bout = (const float*)d_in[9];

    float* out = (float*)d_out;
    float* xo  = out;                               // [B, D]
    float* ldf = out + (size_t)BATCH * DIMS;        // [B]
    float* yo  = ldf + BATCH;                       // [B, D]
    float* ldg = yo + (size_t)BATCH * DIMS;         // [B]

    unsigned short* womask = (unsigned short*)d_ws;           // 2*PF_WOUT bf16
    unsigned short* w1mask = womask + 2 * (size_t)PF_WOUT;    // 2*PF_W1 bf16

    premask_kernel<<<dim3(2048), dim3(256), 0, stream>>>(
        f_Wout, g_Wout, f_W1, g_W1, womask, w1mask);

    flow8_kernel<<<dim3(BATCH / 64, 2), dim3(256), 0, stream>>>(
        x, y, xo, yo,
        w1mask, w1mask + (size_t)PF_W1,
        f_b1, g_b1,
        womask, womask + (size_t)PF_WOUT,
        f_bout, g_bout,
        ldf, ldg);
}

// Round 14
// 397.846 us; speedup vs baseline: 1.0753x; 1.0753x over previous
//
#include <hip/hip_runtime.h>
#include <math.h>

#define BATCH   16384
#define DIMS    64
#define WID     128
#define KN      8
#define NP      23        // 3*KN - 1
#define NCOL    (DIMS * NP)   // 1472 param columns
#define NLAYERS 8
#define BI_F    4.0f
#define GRP     92        // param cols per 4-dim group
#define NGRP    16        // groups per layer
#define NITER   (NLAYERS * NGRP)   // 128 flat groups
#define PCP     104       // Pc row pitch in shorts (208 B, 16B-aligned rows)
#define HHP     72        // Hs-half row pitch in shorts (144 B; 36dw%32=4)
#define XBP     72        // Xb row pitch in shorts (144 B; 36dw%32=4)
#define LOG2E   1.44269504f

#define PF_WOUT (NLAYERS * NCOL * WID)        // per-flow Wout elems: 1,507,328
#define PF_W1   (NLAYERS * WID * DIMS)        // per-flow W1 elems:   65,536

typedef short s16x8 __attribute__((ext_vector_type(8)));
typedef unsigned short u16x8 __attribute__((ext_vector_type(8)));
typedef float f32x4 __attribute__((ext_vector_type(4)));

// Native v_exp_f32 (2^x, ~1 ulp) — exp2f (libm) lowers to OCML's precise
// path with range/denormal handling (several VALU insts per call); the
// builtin is the single HW instruction. 18 calls/eval make this material.
__device__ __forceinline__ float exp2n(float x) {
    return __builtin_amdgcn_exp2f(x);
}

__device__ __forceinline__ unsigned short f2bf(float f) {
    unsigned int u = __builtin_bit_cast(unsigned int, f);
    unsigned int r = (u + 0x7FFFu + ((u >> 16) & 1u)) >> 16;
    return (unsigned short)r;
}
__device__ __forceinline__ float bf2f(unsigned short u) {
    return __builtin_bit_cast(float, (unsigned int)u << 16);
}
// bf16-pair dword -> two f32 (lo: shift up; hi: mask in place).
__device__ __forceinline__ float bfLO(unsigned int u) {
    return __builtin_bit_cast(float, u << 16);
}
__device__ __forceinline__ float bfHI(unsigned int u) {
    return __builtin_bit_cast(float, u & 0xffff0000u);
}
// HW packed f32->bf16 RNE: dst = {bf16(a) lo16, bf16(b) hi16}. 1 inst/pair.
__device__ __forceinline__ unsigned int cvtpk_bf16(float a, float b) {
    unsigned int r;
    asm("v_cvt_pk_bf16_f32 %0, %1, %2" : "=v"(r) : "v"(a), "v"(b));
    return r;
}

// global -> LDS direct DMA, 16B per lane (wave-uniform LDS base + lane*16).
__device__ __forceinline__ void stage16(const unsigned short* g, unsigned short* l) {
    __builtin_amdgcn_global_load_lds(
        (__attribute__((address_space(1))) void*)g,
        (__attribute__((address_space(3))) void*)l,
        16, 0, 0);
}

// ---------------------------------------------------------------------------
// Pre-mask MADE weights -> bf16 workspace (K-swizzled columns, log2e
// pre-scale on womask; unchanged from proven R7-R13 versions).
// ---------------------------------------------------------------------------
__global__ __launch_bounds__(256) void premask_kernel(
    const float* __restrict__ f_wout, const float* __restrict__ g_wout,
    const float* __restrict__ f_w1,   const float* __restrict__ g_w1,
    unsigned short* __restrict__ womask, unsigned short* __restrict__ w1mask)
{
    const int idx    = blockIdx.x * 256 + threadIdx.x;
    const int stride = gridDim.x * 256;

    const int totw = 2 * PF_WOUT;
    for (int i = idx; i < totw; i += stride) {
        int fl = i / PF_WOUT;
        int r  = i % PF_WOUT;
        int h  = r % WID;
        int o  = (r / WID) % NCOL;              // layer-local param col
        int d  = o / NP;
        int hd = h % (DIMS - 1) + 1;            // hid_deg
        const float* src = fl ? g_wout : f_wout;
        unsigned short v = (hd <= d) ? f2bf(src[r] * LOG2E) : (unsigned short)0;
        const int dst = i - h + (h ^ ((o & 7) << 4));   // swizzled k position
        womask[dst] = v;
    }

    const int tot1 = 2 * PF_W1;
    for (int i = idx; i < tot1; i += stride) {
        int fl = i / PF_W1;
        int r  = i % PF_W1;
        int c  = r % DIMS;
        int w  = (r / DIMS) % WID;
        int deg = w % (DIMS - 1) + 1;           // hid_deg
        const float* src = fl ? g_w1 : f_w1;
        w1mask[i] = (c < deg) ? f2bf(src[r]) : (unsigned short)0;
    }
}

// ---------------------------------------------------------------------------
// FUSED 8-layer MAF kernel (R12/R13 structure; R14 = native-exp2 only).
//   Per iteration gi (flat group 0..127):
//     DMA(gi+1 -> Wl[other]) ; [layer start: spline(gi-1); GEMM1(l)]
//     MFMA(gi, Wl[cur]) straight-line with spline(gi-1)
//     Pc-store(gi) ; ONE __syncthreads (drains DMA + Wl-read sync).
// LDS: Wl 47,104 + S 13,312 + Xb 18,432 = 78,848 B -> 2 blocks/CU.
// ---------------------------------------------------------------------------
__global__ __launch_bounds__(256, 2)
void flow8_kernel(
    const float* __restrict__ xin_f, const float* __restrict__ xin_g,
    float* __restrict__ xout_f,      float* __restrict__ xout_g,
    const unsigned short* __restrict__ w1m_f, const unsigned short* __restrict__ w1m_g,
    const float* __restrict__ b1_f,  const float* __restrict__ b1_g,
    const unsigned short* __restrict__ wom_f, const unsigned short* __restrict__ wom_g,
    const float* __restrict__ bo_f,  const float* __restrict__ bo_g,
    float* __restrict__ ld_f,        float* __restrict__ ld_g)
{
    // Wl: double-buffered weight tile [buf][92 cols][128 k] (pre-swizzled).
    __shared__ __align__(16) unsigned short Wl[2][GRP * WID];     // 47,104 B
    // S: per-wave overlay. Pc row-major [16][104] (1664); Hs-HALF view
    //    [16][72] (1152, cols 0..63 then 64..127 sequentially; dead by Pc).
    __shared__ __align__(16) unsigned short S[4][16 * PCP];       // 13,312 B
    // Xb: x ping-pong, BF16, [buf][wv][16 rows][pitch 72].
    __shared__ __align__(16) unsigned short Xb[2][4][16][XBP];    // 18,432 B

    const int t    = threadIdx.x;
    const int wv   = t >> 6;          // wave 0..3
    const int ln   = t & 63;
    const int m    = ln & 15;         // row-in-tile / col-in-tile index
    const int q    = ln >> 4;         // quad
    const int flow = blockIdx.y;
    const int r0   = blockIdx.x * 64 + wv * 16;   // this wave's first batch row

    const float* xin          = flow ? xin_g : xin_f;
    float*       xout         = flow ? xout_g : xout_f;
    const unsigned short* w1m = flow ? w1m_g : w1m_f;
    const float* b1           = flow ? b1_g  : b1_f;
    const unsigned short* wom = flow ? wom_g : wom_f;
    const float* bo           = flow ? bo_g  : bo_f;
    float*       ldp          = flow ? ld_g  : ld_f;

    unsigned short* sw = &S[wv][0];

    // ---- Xb[0] init: wave's 16 rows, f32 global -> bf16 pairs ----
    {
        const int row = ln >> 2;
        const int c0  = (ln & 3) * 16;
        const float* srcr = xin + (size_t)(r0 + row) * DIMS + c0;
        float4 v0 = *(const float4*)(srcr);
        float4 v1 = *(const float4*)(srcr + 4);
        float4 v2 = *(const float4*)(srcr + 8);
        float4 v3 = *(const float4*)(srcr + 12);
        uint4 pa, pb;
        pa.x = cvtpk_bf16(v0.x, v0.y); pa.y = cvtpk_bf16(v0.z, v0.w);
        pa.z = cvtpk_bf16(v1.x, v1.y); pa.w = cvtpk_bf16(v1.z, v1.w);
        pb.x = cvtpk_bf16(v2.x, v2.y); pb.y = cvtpk_bf16(v2.z, v2.w);
        pb.z = cvtpk_bf16(v3.x, v3.y); pb.w = cvtpk_bf16(v3.z, v3.w);
        *(u16x8*)&Xb[0][wv][row][c0]     = __builtin_bit_cast(u16x8, pa);
        *(u16x8*)&Xb[0][wv][row][c0 + 8] = __builtin_bit_cast(u16x8, pb);
    }
    asm volatile("" ::: "memory");

    // ---- prologue: DMA-stage flat group 0 -> Wl[0] ----
    {
        const unsigned short* src = wom + ln * 8;
        #pragma unroll
        for (int i = 0; i < 6; ++i) {
            const int c = wv + 4 * i;
            if (c < 23) stage16(src + c * 512, Wl[0] + c * 512);
        }
    }

    // ---- P-store column map: col o = nt*16+m -> row-major dim*24+j = o+dim.
    int offn[6];
    #pragma unroll
    for (int nt = 0; nt < 6; ++nt) {
        const int o = nt * 16 + m;
        offn[nt] = o + (o >= 23) + (o >= 46) + (o >= 69) + (o >= 92);
    }

    float ldsum = 0.0f;
    s16x8 af[4];
    float bnx[6];

    // ---- GEMM1 (layer l): xa direct-bf16 from Xb[l&1]; H via two 64-col
    //      halves through S (Hs view, pitch 72); sets af[0..3]. ----
    auto gemm1 = [&](int l) {
        const unsigned short* w1m_l = w1m + (size_t)l * WID * DIMS;
        const float* b1_l           = b1 + (size_t)l * WID;
        const unsigned short* xb    = &Xb[l & 1][wv][m][0];
        s16x8 xa0 = *(const s16x8*)(xb + q * 8);
        s16x8 xa1 = *(const s16x8*)(xb + 32 + q * 8);

        f32x4 hacc[8];
        #pragma unroll
        for (int nt = 0; nt < 8; ++nt) {
            float bv = b1_l[nt * 16 + m];
            hacc[nt] = (f32x4){bv, bv, bv, bv};
        }
        #pragma unroll
        for (int nt = 0; nt < 8; ++nt) {
            s16x8 b0 = *(const s16x8*)(w1m_l + (nt * 16 + m) * DIMS + q * 8);
            hacc[nt] = __builtin_amdgcn_mfma_f32_16x16x32_bf16(xa0, b0, hacc[nt], 0, 0, 0);
        }
        #pragma unroll
        for (int nt = 0; nt < 8; ++nt) {
            s16x8 b1f = *(const s16x8*)(w1m_l + (nt * 16 + m) * DIMS + 32 + q * 8);
            hacc[nt] = __builtin_amdgcn_mfma_f32_16x16x32_bf16(xa1, b1f, hacc[nt], 0, 0, 0);
        }
        // half 0: H cols 0..63 (nt 0..3) -> Hs[16][72], read af[0..1]
        #pragma unroll
        for (int nt = 0; nt < 4; ++nt) {
            const int c = nt * 16 + m;
            unsigned int p0 = cvtpk_bf16(fmaxf(hacc[nt][0], 0.0f), fmaxf(hacc[nt][1], 0.0f));
            unsigned int p1 = cvtpk_bf16(fmaxf(hacc[nt][2], 0.0f), fmaxf(hacc[nt][3], 0.0f));
            sw[(q * 4 + 0) * HHP + c] = (unsigned short)p0;
            sw[(q * 4 + 1) * HHP + c] = (unsigned short)(p0 >> 16);
            sw[(q * 4 + 2) * HHP + c] = (unsigned short)p1;
            sw[(q * 4 + 3) * HHP + c] = (unsigned short)(p1 >> 16);
        }
        asm volatile("" ::: "memory");
        af[0] = *(const s16x8*)&sw[m * HHP + q * 8];
        af[1] = *(const s16x8*)&sw[m * HHP + 32 + q * 8];
        asm volatile("" ::: "memory");
        // half 1: H cols 64..127 (nt 4..7) reuse the same region
        #pragma unroll
        for (int nt = 4; nt < 8; ++nt) {
            const int c = (nt - 4) * 16 + m;
            unsigned int p0 = cvtpk_bf16(fmaxf(hacc[nt][0], 0.0f), fmaxf(hacc[nt][1], 0.0f));
            unsigned int p1 = cvtpk_bf16(fmaxf(hacc[nt][2], 0.0f), fmaxf(hacc[nt][3], 0.0f));
            sw[(q * 4 + 0) * HHP + c] = (unsigned short)p0;
            sw[(q * 4 + 1) * HHP + c] = (unsigned short)(p0 >> 16);
            sw[(q * 4 + 2) * HHP + c] = (unsigned short)p1;
            sw[(q * 4 + 3) * HHP + c] = (unsigned short)(p1 >> 16);
        }
        asm volatile("" ::: "memory");
        af[2] = *(const s16x8*)&sw[m * HHP + q * 8];
        af[3] = *(const s16x8*)&sw[m * HHP + 32 + q * 8];
        asm volatile("" ::: "memory");
    };

    // ---- spline for flat group pgi (reads Pc stored at iter pgi) ----
    auto spline = [&](int pgi) {
        const int pl = pgi >> 4;
        const int pg = pgi & 15;
        const int d  = pg * 4 + q;
        const int xb = pl & 1;

        const unsigned short* pr = &sw[m * PCP + q * 24];
        u16x8 w0 = *(const u16x8*)(pr);
        u16x8 w1 = *(const u16x8*)(pr + 8);
        u16x8 w2 = *(const u16x8*)(pr + 16);
        uint4 r0 = __builtin_bit_cast(uint4, w0);
        uint4 r1 = __builtin_bit_cast(uint4, w1);
        uint4 r2 = __builtin_bit_cast(uint4, w2);

        float pp[NP];
        pp[0]  = bfLO(r0.x); pp[1]  = bfHI(r0.x);
        pp[2]  = bfLO(r0.y); pp[3]  = bfHI(r0.y);
        pp[4]  = bfLO(r0.z); pp[5]  = bfHI(r0.z);
        pp[6]  = bfLO(r0.w); pp[7]  = bfHI(r0.w);
        pp[8]  = bfLO(r1.x); pp[9]  = bfHI(r1.x);
        pp[10] = bfLO(r1.y); pp[11] = bfHI(r1.y);
        pp[12] = bfLO(r1.z); pp[13] = bfHI(r1.z);
        pp[14] = bfLO(r1.w); pp[15] = bfHI(r1.w);
        pp[16] = bfLO(r2.x); pp[17] = bfHI(r2.x);
        pp[18] = bfLO(r2.y); pp[19] = bfHI(r2.y);
        pp[20] = bfLO(r2.z); pp[21] = bfHI(r2.z);
        pp[22] = bfLO(r2.w);

        const float xraw = bf2f(Xb[xb][wv][m][d]);

        float ew[KN], eh[KN];
        #pragma unroll
        for (int j = 0; j < KN; ++j) {
            ew[j] = exp2n(pp[j]);
            eh[j] = exp2n(pp[8 + j]);
        }
        const float sw_ = ((ew[0] + ew[1]) + (ew[2] + ew[3]))
                        + ((ew[4] + ew[5]) + (ew[6] + ew[7]));
        const float sh_ = ((eh[0] + eh[1]) + (eh[2] + eh[3]))
                        + ((eh[4] + eh[5]) + (eh[6] + eh[7]));
        const float cmul = 8.0f / 1.01f;
        const float cadd = 0.00125f * (8.0f / 1.01f);
        const float rw = cmul / sw_, rh = cmul / sh_;
        float width[KN], height[KN];
        #pragma unroll
        for (int j = 0; j < KN; ++j) {
            width[j]  = fmaf(ew[j], rw, cadd);
            height[j] = fmaf(eh[j], rh, cadd);
        }

        const bool inside = (xraw > -BI_F) && (xraw < BI_F);
        const float xcl = fminf(fmaxf(xraw, -BI_F), BI_F);

        // Knot scan, i=0 peeled; tracks SELECTED raw deriv params; softplus
        // deferred to the 2 selected (cc monotone: cc1 <=> k>=1, cc7 <=> k==7).
        float cx = -BI_F + width[0], cy = -BI_F + height[0];
        float xk = -BI_F, yk = -BI_F, xk1 = cx, yk1 = cy;
        float selk = pp[16], selk1 = pp[16];
        bool cc1 = false, cc7 = false;
        #pragma unroll
        for (int i = 1; i < KN; ++i) {
            const float nx = cx + width[i];
            const float ny = cy + height[i];
            const bool cc = (xcl >= cx);
            if (i == 1) cc1 = cc;
            if (i == 7) cc7 = cc;
            xk  = cc ? cx : xk;    yk  = cc ? cy : yk;
            xk1 = cc ? nx : xk1;   yk1 = cc ? ny : yk1;
            selk = cc ? pp[15 + i] : selk;
            if (i < 7) selk1 = cc ? pp[16 + i] : selk1;
            cx = nx; cy = ny;
        }
        const float ta = exp2n(selk);
        const float da = fmaf(__log2f(1.0f + ta), 0.69314718f, 0.001f);
        const float tb = exp2n(selk1);
        const float db = fmaf(__log2f(1.0f + tb), 0.69314718f, 0.001f);
        const float dk  = cc1 ? da : 1.0f;
        const float dk1 = cc7 ? 1.0f : db;

        const float invw = 1.0f / (xk1 - xk);
        const float sk   = (yk1 - yk) * invw;
        const float xi   = (xcl - xk) * invw;
        const float omx  = 1.0f - xi;
        const float den  = sk + (dk1 + dk - 2.0f * sk) * xi * omx;
        const float rden = 1.0f / den;
        float outv = fmaf((yk1 - yk) * (sk * xi * xi + dk * xi * omx), rden, yk);
        const float numl = dk1 * xi * xi + 2.0f * sk * xi * omx + dk * omx * omx;
        float ldj = __logf(sk * sk * numl * rden * rden);
        outv = inside ? outv : xraw;
        ldj  = inside ? ldj : 0.0f;

        Xb[xb ^ 1][wv][m][63 - d] = (unsigned short)cvtpk_bf16(outv, outv);
        ldsum += ldj;
    };

    // ---- prologue: GEMM1 layer 0 (covers DMA g0) + bias(0) ----
    gemm1(0);
    #pragma unroll
    for (int nt = 0; nt < 6; ++nt)
        bnx[nt] = bo[nt * 16 + m] * LOG2E;     // gi=0 cols 0..95 in-bounds

    __syncthreads();                 // g0 weights resident for all waves

    #pragma unroll 1
    for (int gi = 0; gi < NITER; ++gi) {
        const int g = gi & 15;

        // ---- issue DMA for gi+1 into the idle buffer (drained at the
        //      barrier below; full-iteration latency window) ----
        if (gi < NITER - 1) {
            const int n = gi + 1, l2 = n >> 4, g2 = n & 15;
            const unsigned short* src = wom +
                ((size_t)l2 * NCOL + (size_t)g2 * GRP) * WID + ln * 8;
            unsigned short* dst = &Wl[n & 1][0];
            #pragma unroll
            for (int i = 0; i < 6; ++i) {
                const int c = wv + 4 * i;
                if (c < 23) stage16(src + c * 512, dst + c * 512);
            }
        }

        // ---- layer start: finish previous group's spline (reads Pc before
        //      GEMM1's Hs overwrites it), then GEMM1 for this layer ----
        if (g == 0 && gi > 0) {
            spline(gi - 1);
            asm volatile("" ::: "memory");
            gemm1(gi >> 4);
        }

        // ---- MFMA group gi from Wl[gi&1] (swizzled) ----
        f32x4 acc[6];
        #pragma unroll
        for (int nt = 0; nt < 6; ++nt)
            acc[nt] = (f32x4){bnx[nt], bnx[nt], bnx[nt], bnx[nt]};

        const unsigned short* wl = &Wl[gi & 1][0];
        const int swz = ((g * 4 + m) & 7) << 4;
        #pragma unroll
        for (int ks = 0; ks < 4; ++ks) {
            #pragma unroll
            for (int nt = 0; nt < 6; ++nt) {
                const s16x8 bfr = *(const s16x8*)&wl[
                    (nt * 16 + m) * WID + ((ks * 32 + q * 8) ^ swz)];
                acc[nt] = __builtin_amdgcn_mfma_f32_16x16x32_bf16(af[ks], bfr, acc[nt], 0, 0, 0);
            }
        }

        // ---- bias prefetch for gi+1 (bnx consumed above) ----
        if (gi < NITER - 1) {
            const int n = gi + 1, l2 = n >> 4, g2 = n & 15;
            #pragma unroll
            for (int nt = 0; nt < 6; ++nt) {
                int o = g2 * GRP + nt * 16 + m;
                o = (o < NCOL) ? o : (NCOL - 1);
                bnx[nt] = bo[(size_t)l2 * NCOL + o] * LOG2E;
            }
        }

        // ---- mid-layer: spline(gi-1), straight-line with the MFMA above ----
        if (g != 0) {
            spline(gi - 1);
        }
        asm volatile("" ::: "memory");   // spline Pc reads before Pc overwrite

        // ---- Pc store (row-major, pitch 104) from acc ----
        #pragma unroll
        for (int nt = 0; nt < 6; ++nt) {
            const int cb = q * 4 * PCP + offn[nt];
            unsigned int p0 = cvtpk_bf16(acc[nt][0], acc[nt][1]);
            unsigned int p1 = cvtpk_bf16(acc[nt][2], acc[nt][3]);
            sw[cb          ] = (unsigned short)p0;
            sw[cb +     PCP] = (unsigned short)(p0 >> 16);
            sw[cb + 2 * PCP] = (unsigned short)p1;
            sw[cb + 3 * PCP] = (unsigned short)(p1 >> 16);
        }

        __syncthreads();   // sync Wl reads + drain DMA(gi+1) for all waves
    }

    // ---- drain: last group's spline ----
    spline(NITER - 1);
    asm volatile("" ::: "memory");

    // ---- epilogue: xout (f32) from final Xb[0] (layer 8 -> buf 8&1 = 0) ----
    {
        const int row = ln >> 2;
        const int c0  = (ln & 3) * 16;
        u16x8 ua = *(const u16x8*)&Xb[0][wv][row][c0];
        u16x8 ub = *(const u16x8*)&Xb[0][wv][row][c0 + 8];
        uint4 ra = __builtin_bit_cast(uint4, ua);
        uint4 rb = __builtin_bit_cast(uint4, ub);
        float* dstr = xout + (size_t)(r0 + row) * DIMS + c0;
        float4 o0 = {bfLO(ra.x), bfHI(ra.x), bfLO(ra.y), bfHI(ra.y)};
        float4 o1 = {bfLO(ra.z), bfHI(ra.z), bfLO(ra.w), bfHI(ra.w)};
        float4 o2 = {bfLO(rb.x), bfHI(rb.x), bfLO(rb.y), bfHI(rb.y)};
        float4 o3 = {bfLO(rb.z), bfHI(rb.z), bfLO(rb.w), bfHI(rb.w)};
        *(float4*)(dstr)      = o0;
        *(float4*)(dstr + 4)  = o1;
        *(float4*)(dstr + 8)  = o2;
        *(float4*)(dstr + 12) = o3;
    }

    // ---- ld: reduce q-quarters, one plain store per row ----
    float v = ldsum + __shfl_xor(ldsum, 16, 64);
    v = v + __shfl_xor(v, 32, 64);
    if (ln < 16) {
        ldp[r0 + ln] = v;
    }
}

// ---------------------------------------------------------------------------
extern "C" void kernel_launch(void* const* d_in, const int* in_sizes, int n_in,
                              void* d_out, int out_size, void* d_ws, size_t ws_size,
                              hipStream_t stream)
{
    const float* x      = (const float*)d_in[0];
    const float* y      = (const float*)d_in[1];
    const float* f_W1   = (const float*)d_in[2];
    const float* f_b1   = (const float*)d_in[3];
    const float* f_Wout = (const float*)d_in[4];
    const float* f_bout = (const float*)d_in[5];
    const float* g_W1   = (const float*)d_in[6];
    const float* g_b1   = (const float*)d_in[7];
    const float* g_Wout = (const float*)d_in[8];
    const float* g_bout = (const float*)d_in[9];

    float* out = (float*)d_out;
    float* xo  = out;                               // [B, D]
    float* ldf = out + (size_t)BATCH * DIMS;        // [B]
    float* yo  = ldf + BATCH;                       // [B, D]
    float* ldg = yo + (size_t)BATCH * DIMS;         // [B]

    unsigned short* womask = (unsigned short*)d_ws;           // 2*PF_WOUT bf16
    unsigned short* w1mask = womask + 2 * (size_t)PF_WOUT;    // 2*PF_W1 bf16

    premask_kernel<<<dim3(2048), dim3(256), 0, stream>>>(
        f_Wout, g_Wout, f_W1, g_W1, womask, w1mask);

    flow8_kernel<<<dim3(BATCH / 64, 2), dim3(256), 0, stream>>>(
        x, y, xo, yo,
        w1mask, w1mask + (size_t)PF_W1,
        f_b1, g_b1,
        womask, womask + (size_t)PF_WOUT,
        f_bout, g_bout,
        ldf, ldg);
}